// Round 1
// baseline (253.069 us; speedup 1.0000x reference)
//
#include <hip/hip_runtime.h>

#define N_NODES 100000
#define DEG 16
#define IN_F 128
#define OUT_F 64
#define E_EDGES (N_NODES * DEG)

typedef __bf16 bf16x8 __attribute__((ext_vector_type(8)));
typedef unsigned short u16x8 __attribute__((ext_vector_type(8)));
typedef float f32x4 __attribute__((ext_vector_type(4)));

union BF8 { u16x8 u; bf16x8 b; };

__device__ inline float bf2f(unsigned short u) {
    union { unsigned int i; float f; } v; v.i = ((unsigned int)u) << 16; return v.f;
}
__device__ inline unsigned short f2bf(float f) {
    union { float f; unsigned int i; } v; v.f = f;
    unsigned int r = (v.i + 0x7FFFu + ((v.i >> 16) & 1u)) >> 16;
    return (unsigned short)r;
}

// ---------------- Kernel A: h_high = in @ W_high, h_low = in @ W_low (bf16 out) ----
// wave = 16 rows; LDS holds W^T (64 x 128, stride 136 bf16) for ds_read_b128 frags.
__global__ __launch_bounds__(256) void k_gemm(
    const float* __restrict__ in, const float* __restrict__ Wh,
    const float* __restrict__ Wl, unsigned short* __restrict__ h_high,
    unsigned short* __restrict__ h_low)
{
    __shared__ unsigned short ldsW[2][64][136];  // 34.8 KB
    for (int idx = threadIdx.x; idx < IN_F * OUT_F; idx += 256) {
        int k = idx >> 6, n = idx & 63;
        ldsW[0][n][k] = f2bf(Wh[idx]);
        ldsW[1][n][k] = f2bf(Wl[idx]);
    }
    __syncthreads();

    int wave = blockIdx.x * 4 + (threadIdx.x >> 6);
    int lane = threadIdx.x & 63;
    int row0 = wave * 16;
    if (row0 >= N_NODES) return;

    int quad = lane >> 4;
    int mrow = row0 + (lane & 15);
    int lrow = mrow < N_NODES ? mrow : (N_NODES - 1);

    // A fragments: lane holds A[m=lane&15][k = quad*8 + j], j=0..7, per 32-wide k-block
    bf16x8 afrag[4];
    const float* inrow = in + (size_t)lrow * IN_F + quad * 8;
    #pragma unroll
    for (int kb = 0; kb < 4; kb++) {
        f32x4 v0 = *(const f32x4*)(inrow + kb * 32);
        f32x4 v1 = *(const f32x4*)(inrow + kb * 32 + 4);
        bf16x8 a;
        #pragma unroll
        for (int j = 0; j < 4; j++) { a[j] = (__bf16)v0[j]; a[4 + j] = (__bf16)v1[j]; }
        afrag[kb] = a;
    }

    f32x4 acc[2][4];
    #pragma unroll
    for (int m = 0; m < 2; m++)
        #pragma unroll
        for (int ct = 0; ct < 4; ct++) acc[m][ct] = (f32x4){0, 0, 0, 0};

    #pragma unroll
    for (int kb = 0; kb < 4; kb++) {
        #pragma unroll
        for (int ct = 0; ct < 4; ct++) {
            int n = ct * 16 + (lane & 15);
            BF8 bh, bl;
            bh.u = *(const u16x8*)&ldsW[0][n][kb * 32 + quad * 8];
            bl.u = *(const u16x8*)&ldsW[1][n][kb * 32 + quad * 8];
            acc[0][ct] = __builtin_amdgcn_mfma_f32_16x16x32_bf16(afrag[kb], bh.b, acc[0][ct], 0, 0, 0);
            acc[1][ct] = __builtin_amdgcn_mfma_f32_16x16x32_bf16(afrag[kb], bl.b, acc[1][ct], 0, 0, 0);
        }
    }

    // C/D: col = lane&15 (+16*ct), row = quad*4 + reg
    #pragma unroll
    for (int r = 0; r < 4; r++) {
        int row = row0 + quad * 4 + r;
        if (row >= N_NODES) continue;
        size_t base = (size_t)row * OUT_F + (lane & 15);
        #pragma unroll
        for (int ct = 0; ct < 4; ct++) {
            h_high[base + ct * 16] = f2bf(acc[0][ct][r]);
            h_low [base + ct * 16] = f2bf(acc[1][ct][r]);
        }
    }
}

// ---------------- Kernel B: h_agg (bf16) + per-node attention scalars (float4) ----
__global__ __launch_bounds__(256) void k_agg(
    const unsigned short* __restrict__ h_high, const unsigned short* __restrict__ h_low,
    const int* __restrict__ dst, const float* __restrict__ ah, const float* __restrict__ al,
    unsigned short* __restrict__ hagg_h, unsigned short* __restrict__ hagg_l,
    f32x4* __restrict__ s)
{
    int node = blockIdx.x * 4 + (threadIdx.x >> 6);
    if (node >= N_NODES) return;
    int lane = threadIdx.x & 63;

    int jl = dst[node * DEG + (lane & 15)];
    float hh = bf2f(h_high[(size_t)node * 64 + lane]);
    float hl = bf2f(h_low [(size_t)node * 64 + lane]);

    float sh = 16.0f * hh;   // DEG * h[i] (self-loop is among the 16 dst too)
    float sl = 16.0f * hl;
    #pragma unroll
    for (int e = 0; e < DEG; e++) {
        int j = __shfl(jl, e);
        sh += bf2f(h_high[(size_t)j * 64 + lane]);
        sl -= bf2f(h_low [(size_t)j * 64 + lane]);
    }
    hagg_h[(size_t)node * 64 + lane] = f2bf(sh);
    hagg_l[(size_t)node * 64 + lane] = f2bf(sl);

    float ph = hh * ah[lane];
    float qh = hh * ah[64 + lane];
    float pl = hl * al[lane];
    float ql = hl * al[64 + lane];
    #pragma unroll
    for (int o = 32; o > 0; o >>= 1) {
        ph += __shfl_xor(ph, o);
        qh += __shfl_xor(qh, o);
        pl += __shfl_xor(pl, o);
        ql += __shfl_xor(ql, o);
    }
    if (lane == 0) s[node] = (f32x4){ph, qh, pl, ql};
}

// ---------------- Kernel C: softmax-weighted aggregate + relu6 ----
__global__ __launch_bounds__(256) void k_out(
    const unsigned short* __restrict__ hagg_h, const unsigned short* __restrict__ hagg_l,
    const int* __restrict__ dst, const f32x4* __restrict__ s,
    float* __restrict__ out)
{
    int node = blockIdx.x * 4 + (threadIdx.x >> 6);
    if (node >= N_NODES) return;
    int lane = threadIdx.x & 63;

    int jl = dst[node * DEG + (lane & 15)];
    f32x4 si = s[node];
    float acc_h = 0.0f, acc_l = 0.0f, rs_h = 0.0f, rs_l = 0.0f;
    #pragma unroll
    for (int e = 0; e < DEG; e++) {
        int j = __shfl(jl, e);
        f32x4 sj = s[j];
        float xh = si.x + sj.y;           // p_high[i] + q_high[j]
        float xl = si.z + sj.w;
        float lh = xh > 0.0f ? xh : 0.2f * xh;
        float ll = xl > 0.0f ? xl : 0.2f * xl;
        float wh = __expf(-lh);
        float wl = __expf(-ll);
        rs_h += wh;                       // rowsum uses RAW exp values
        rs_l += wl;
        float eh = fminf(wh, 6.0f);       // relu6 on weights (exp>0 so max side only)
        float el = fminf(wl, 6.0f);
        acc_h += eh * bf2f(hagg_h[(size_t)j * 64 + lane]);
        acc_l += el * bf2f(hagg_l[(size_t)j * 64 + lane]);
    }
    float r = 0.5f * (acc_h / rs_h + acc_l / rs_l);
    r = fminf(fmaxf(r, 0.0f), 6.0f);
    out[(size_t)node * 64 + lane] = r;
}

extern "C" void kernel_launch(void* const* d_in, const int* in_sizes, int n_in,
                              void* d_out, int out_size, void* d_ws, size_t ws_size,
                              hipStream_t stream) {
    const float* input = (const float*)d_in[0];
    const int*   edge  = (const int*)d_in[1];     // [2, E]: src then dst
    const float* Wh    = (const float*)d_in[2];
    const float* Wl    = (const float*)d_in[3];
    const float* ah    = (const float*)d_in[4];
    const float* al    = (const float*)d_in[5];
    float* out = (float*)d_out;

    unsigned short* h_high = (unsigned short*)d_ws;
    unsigned short* h_low  = h_high + (size_t)N_NODES * 64;
    unsigned short* hagg_h = h_low  + (size_t)N_NODES * 64;
    unsigned short* hagg_l = hagg_h + (size_t)N_NODES * 64;
    f32x4* s = (f32x4*)(hagg_l + (size_t)N_NODES * 64);   // 51.2e6 B offset, 16B aligned

    const int* dstp = edge + E_EDGES;

    k_gemm<<<1563, 256, 0, stream>>>(input, Wh, Wl, h_high, h_low);   // 6252 waves x 16 rows
    k_agg<<<N_NODES / 4, 256, 0, stream>>>(h_high, h_low, dstp, ah, al, hagg_h, hagg_l, s);
    k_out<<<N_NODES / 4, 256, 0, stream>>>(hagg_h, hagg_l, dstp, s, out);
}

// Round 3
// 233.478 us; speedup vs baseline: 1.0839x; 1.0839x over previous
//
#include <hip/hip_runtime.h>

#define N_NODES 100000
#define DEG 16
#define IN_F 128
#define OUT_F 64
#define E_EDGES (N_NODES * DEG)

typedef __bf16 bf16x8 __attribute__((ext_vector_type(8)));
typedef unsigned short u16x8 __attribute__((ext_vector_type(8)));
typedef float f32x4 __attribute__((ext_vector_type(4)));

union BF8 { u16x8 u; bf16x8 b; };

__device__ inline float lo_bf(unsigned int u) {
    union { unsigned int i; float f; } v; v.i = u << 16; return v.f;
}
__device__ inline float hi_bf(unsigned int u) {
    union { unsigned int i; float f; } v; v.i = u & 0xFFFF0000u; return v.f;
}
__device__ inline unsigned short f2bf(float f) {
    union { float f; unsigned int i; } v; v.f = f;
    return (unsigned short)((v.i + 0x7FFFu + ((v.i >> 16) & 1u)) >> 16);
}
__device__ inline unsigned int packbf(float a, float b) {
    return (unsigned int)f2bf(a) | ((unsigned int)f2bf(b) << 16);
}

// ---------------- Kernel A: H[row][n] = pack(bf16(in@Wh), bf16(in@Wl)) ----
// Identical to the R1-proven GEMM; only the store is changed to packed u32.
__global__ __launch_bounds__(256) void k_gemm(
    const float* __restrict__ in, const float* __restrict__ Wh,
    const float* __restrict__ Wl, unsigned int* __restrict__ H)
{
    __shared__ unsigned short ldsW[2][64][136];  // 34.8 KB
    for (int idx = threadIdx.x; idx < IN_F * OUT_F; idx += 256) {
        int k = idx >> 6, n = idx & 63;
        ldsW[0][n][k] = f2bf(Wh[idx]);
        ldsW[1][n][k] = f2bf(Wl[idx]);
    }
    __syncthreads();

    int wave = blockIdx.x * 4 + (threadIdx.x >> 6);
    int lane = threadIdx.x & 63;
    int row0 = wave * 16;
    if (row0 >= N_NODES) return;

    int quad = lane >> 4, c = lane & 15;
    int mrow = row0 + c;
    int lrow = mrow < N_NODES ? mrow : (N_NODES - 1);

    // A fragment: lane holds A[m=c][k = quad*8 + j] per 32-wide k-block
    bf16x8 afrag[4];
    const float* inrow = in + (size_t)lrow * IN_F + quad * 8;
    #pragma unroll
    for (int kb = 0; kb < 4; kb++) {
        f32x4 v0 = *(const f32x4*)(inrow + kb * 32);
        f32x4 v1 = *(const f32x4*)(inrow + kb * 32 + 4);
        bf16x8 a;
        #pragma unroll
        for (int j = 0; j < 4; j++) { a[j] = (__bf16)v0[j]; a[4 + j] = (__bf16)v1[j]; }
        afrag[kb] = a;
    }

    f32x4 acc[2][4];
    #pragma unroll
    for (int m = 0; m < 2; m++)
        #pragma unroll
        for (int t = 0; t < 4; t++) acc[m][t] = (f32x4){0, 0, 0, 0};

    #pragma unroll
    for (int kb = 0; kb < 4; kb++) {
        #pragma unroll
        for (int t = 0; t < 4; t++) {
            int n = t * 16 + c;
            BF8 bh, bl;
            bh.u = *(const u16x8*)&ldsW[0][n][kb * 32 + quad * 8];
            bl.u = *(const u16x8*)&ldsW[1][n][kb * 32 + quad * 8];
            acc[0][t] = __builtin_amdgcn_mfma_f32_16x16x32_bf16(afrag[kb], bh.b, acc[0][t], 0, 0, 0);
            acc[1][t] = __builtin_amdgcn_mfma_f32_16x16x32_bf16(afrag[kb], bl.b, acc[1][t], 0, 0, 0);
        }
    }

    // C/D: col = t*16 + c, row = quad*4 + r  (R1-proven mapping), packed store
    #pragma unroll
    for (int r = 0; r < 4; r++) {
        int row = row0 + quad * 4 + r;
        if (row >= N_NODES) continue;
        size_t base = (size_t)row * OUT_F + c;
        #pragma unroll
        for (int t = 0; t < 4; t++)
            H[base + t * 16] = packbf(acc[0][t][r], acc[1][t][r]);
    }
}

// ---------------- Kernel B: HAGG + attention scalars s (R1 logic, packed io) ----
__global__ __launch_bounds__(256) void k_agg(
    const unsigned int* __restrict__ H, const int* __restrict__ dst,
    const float* __restrict__ ah, const float* __restrict__ al,
    unsigned int* __restrict__ HAGG, f32x4* __restrict__ s)
{
    int node = blockIdx.x * 4 + (threadIdx.x >> 6);
    int lane = threadIdx.x & 63;

    int jl = dst[node * DEG + (lane & 15)];
    unsigned int hu = H[(size_t)node * 64 + lane];
    float hh = lo_bf(hu);
    float hl = hi_bf(hu);

    float sh = 16.0f * hh;   // DEG * h[i] (self-loop among the 16 dst)
    float sl = 16.0f * hl;
    #pragma unroll
    for (int t = 0; t < DEG; t++) {
        int j = __shfl(jl, t);
        unsigned int u = H[(size_t)j * 64 + lane];
        sh += lo_bf(u);
        sl -= hi_bf(u);
    }
    HAGG[(size_t)node * 64 + lane] = packbf(sh, sl);

    float ph = hh * ah[lane];
    float qh = hh * ah[64 + lane];
    float pl = hl * al[lane];
    float ql = hl * al[64 + lane];
    #pragma unroll
    for (int o = 32; o > 0; o >>= 1) {
        ph += __shfl_xor(ph, o);
        qh += __shfl_xor(qh, o);
        pl += __shfl_xor(pl, o);
        ql += __shfl_xor(ql, o);
    }
    if (lane == 0) s[node] = (f32x4){ph, qh, pl, ql};
}

// ---------------- Kernel C: weighted aggregate + relu6 (per-lane edge weights) ----
__global__ __launch_bounds__(256) void k_out(
    const unsigned int* __restrict__ HAGG, const int* __restrict__ dst,
    const f32x4* __restrict__ s, float* __restrict__ out)
{
    int node = blockIdx.x * 4 + (threadIdx.x >> 6);
    int lane = threadIdx.x & 63;

    int jl = dst[node * DEG + (lane & 15)];   // lane e<16 holds edge e; 16..63 dup
    f32x4 si = s[node];                       // wave-uniform
    f32x4 sj = s[jl];
    float xh = si.x + sj.y;                   // p_high[i] + q_high[j]
    float xl = si.z + sj.w;
    float lh = xh > 0.0f ? xh : 0.2f * xh;
    float ll = xl > 0.0f ? xl : 0.2f * xl;
    float wh = __expf(-lh);
    float wl = __expf(-ll);
    float rh = wh, rl = wl;                   // rowsum over RAW exp values
    #pragma unroll
    for (int o = 8; o > 0; o >>= 1) { rh += __shfl_xor(rh, o); rl += __shfl_xor(rl, o); }
    float eh = fminf(wh, 6.0f);               // relu6 on weights
    float el = fminf(wl, 6.0f);

    float acc_h = 0.0f, acc_l = 0.0f;
    #pragma unroll
    for (int t = 0; t < DEG; t++) {
        int j = __shfl(jl, t);
        unsigned int u = HAGG[(size_t)j * 64 + lane];
        acc_h += __shfl(eh, t) * lo_bf(u);
        acc_l += __shfl(el, t) * hi_bf(u);
    }
    float r = 0.5f * (acc_h / rh + acc_l / rl);
    r = fminf(fmaxf(r, 0.0f), 6.0f);
    out[(size_t)node * 64 + lane] = r;
}

extern "C" void kernel_launch(void* const* d_in, const int* in_sizes, int n_in,
                              void* d_out, int out_size, void* d_ws, size_t ws_size,
                              hipStream_t stream) {
    const float* input = (const float*)d_in[0];
    const int*   edge  = (const int*)d_in[1];     // [2, E]: src then dst
    const float* Wh    = (const float*)d_in[2];
    const float* Wl    = (const float*)d_in[3];
    const float* ah    = (const float*)d_in[4];
    const float* al    = (const float*)d_in[5];
    float* out = (float*)d_out;

    unsigned int* H    = (unsigned int*)d_ws;                    // 25.6 MB
    unsigned int* HAGG = H + (size_t)N_NODES * 64;               // 25.6 MB
    f32x4* s = (f32x4*)(HAGG + (size_t)N_NODES * 64);            // 1.6 MB

    const int* dstp = edge + E_EDGES;

    k_gemm<<<1563, 256, 0, stream>>>(input, Wh, Wl, H);
    k_agg<<<N_NODES / 4, 256, 0, stream>>>(H, dstp, ah, al, HAGG, s);
    k_out<<<N_NODES / 4, 256, 0, stream>>>(HAGG, dstp, s, out);
}

// Round 4
// 232.628 us; speedup vs baseline: 1.0879x; 1.0037x over previous
//
#include <hip/hip_runtime.h>

#define N_NODES 100000
#define DEG 16
#define IN_F 128
#define OUT_F 64
#define E_EDGES (N_NODES * DEG)

typedef __bf16 bf16x8 __attribute__((ext_vector_type(8)));
typedef unsigned short u16x8 __attribute__((ext_vector_type(8)));
typedef float f32x4 __attribute__((ext_vector_type(4)));

union BF8 { u16x8 u; bf16x8 b; };

__device__ inline float lo_bf(unsigned int u) {
    union { unsigned int i; float f; } v; v.i = u << 16; return v.f;
}
__device__ inline float hi_bf(unsigned int u) {
    union { unsigned int i; float f; } v; v.i = u & 0xFFFF0000u; return v.f;
}
__device__ inline unsigned short f2bf(float f) {
    union { float f; unsigned int i; } v; v.f = f;
    return (unsigned short)((v.i + 0x7FFFu + ((v.i >> 16) & 1u)) >> 16);
}
__device__ inline unsigned int packbf(float a, float b) {
    return (unsigned int)f2bf(a) | ((unsigned int)f2bf(b) << 16);
}

// ---------------- Kernel A: H[row][n] = pack(bf16(in@Wh), bf16(in@Wl)) ----
// (R1/R3-proven; packed u32 stores)
__global__ __launch_bounds__(256) void k_gemm(
    const float* __restrict__ in, const float* __restrict__ Wh,
    const float* __restrict__ Wl, unsigned int* __restrict__ H)
{
    __shared__ unsigned short ldsW[2][64][136];  // 34.8 KB
    for (int idx = threadIdx.x; idx < IN_F * OUT_F; idx += 256) {
        int k = idx >> 6, n = idx & 63;
        ldsW[0][n][k] = f2bf(Wh[idx]);
        ldsW[1][n][k] = f2bf(Wl[idx]);
    }
    __syncthreads();

    int wave = blockIdx.x * 4 + (threadIdx.x >> 6);
    int lane = threadIdx.x & 63;
    int row0 = wave * 16;
    if (row0 >= N_NODES) return;

    int quad = lane >> 4, c = lane & 15;
    int mrow = row0 + c;
    int lrow = mrow < N_NODES ? mrow : (N_NODES - 1);

    bf16x8 afrag[4];
    const float* inrow = in + (size_t)lrow * IN_F + quad * 8;
    #pragma unroll
    for (int kb = 0; kb < 4; kb++) {
        f32x4 v0 = *(const f32x4*)(inrow + kb * 32);
        f32x4 v1 = *(const f32x4*)(inrow + kb * 32 + 4);
        bf16x8 a;
        #pragma unroll
        for (int j = 0; j < 4; j++) { a[j] = (__bf16)v0[j]; a[4 + j] = (__bf16)v1[j]; }
        afrag[kb] = a;
    }

    f32x4 acc[2][4];
    #pragma unroll
    for (int m = 0; m < 2; m++)
        #pragma unroll
        for (int t = 0; t < 4; t++) acc[m][t] = (f32x4){0, 0, 0, 0};

    #pragma unroll
    for (int kb = 0; kb < 4; kb++) {
        #pragma unroll
        for (int t = 0; t < 4; t++) {
            int n = t * 16 + c;
            BF8 bh, bl;
            bh.u = *(const u16x8*)&ldsW[0][n][kb * 32 + quad * 8];
            bl.u = *(const u16x8*)&ldsW[1][n][kb * 32 + quad * 8];
            acc[0][t] = __builtin_amdgcn_mfma_f32_16x16x32_bf16(afrag[kb], bh.b, acc[0][t], 0, 0, 0);
            acc[1][t] = __builtin_amdgcn_mfma_f32_16x16x32_bf16(afrag[kb], bl.b, acc[1][t], 0, 0, 0);
        }
    }

    #pragma unroll
    for (int r = 0; r < 4; r++) {
        int row = row0 + quad * 4 + r;
        if (row >= N_NODES) continue;
        size_t base = (size_t)row * OUT_F + c;
        #pragma unroll
        for (int t = 0; t < 4; t++)
            H[base + t * 16] = packbf(acc[0][t][r], acc[1][t][r]);
    }
}

// ---------------- Kernel B: HAGG + attention scalars s ----
// node forced wave-uniform -> dst row via scalar loads; gathers batch-issued.
__global__ __launch_bounds__(256) void k_agg(
    const unsigned int* __restrict__ H, const int* __restrict__ dst,
    const float* __restrict__ ah, const float* __restrict__ al,
    unsigned int* __restrict__ HAGG, f32x4* __restrict__ s)
{
    int lane = threadIdx.x & 63;
    int node = __builtin_amdgcn_readfirstlane(blockIdx.x * 4 + (threadIdx.x >> 6));
    const int* dp = dst + node * DEG;   // 64-B aligned row, scalar loads

    unsigned int hu = H[(size_t)node * 64 + lane];
    float hh = lo_bf(hu);
    float hl = hi_bf(hu);
    float sh = 16.0f * hh;   // DEG * h[i] (self-loop among the 16 dst)
    float sl = 16.0f * hl;

    #pragma unroll
    for (int half = 0; half < 2; half++) {
        unsigned int u[8];
        #pragma unroll
        for (int t = 0; t < 8; t++) {
            int j = dp[half * 8 + t];                 // SGPR
            u[t] = H[(size_t)j * 64 + lane];          // 8 independent loads in flight
        }
        #pragma unroll
        for (int t = 0; t < 8; t++) { sh += lo_bf(u[t]); sl -= hi_bf(u[t]); }
    }
    HAGG[(size_t)node * 64 + lane] = packbf(sh, sl);

    float ph = hh * ah[lane];
    float qh = hh * ah[64 + lane];
    float pl = hl * al[lane];
    float ql = hl * al[64 + lane];
    #pragma unroll
    for (int o = 32; o > 0; o >>= 1) {
        ph += __shfl_xor(ph, o);
        qh += __shfl_xor(qh, o);
        pl += __shfl_xor(pl, o);
        ql += __shfl_xor(ql, o);
    }
    if (lane == 0) s[node] = (f32x4){ph, qh, pl, ql};
}

// ---------------- Kernel C: weighted aggregate + relu6 ----
__global__ __launch_bounds__(256) void k_out(
    const unsigned int* __restrict__ HAGG, const int* __restrict__ dst,
    const f32x4* __restrict__ s, float* __restrict__ out)
{
    int lane = threadIdx.x & 63;
    int node = __builtin_amdgcn_readfirstlane(blockIdx.x * 4 + (threadIdx.x >> 6));
    const int* dp = dst + node * DEG;

    int jl = dp[lane & 15];                   // lane e<16 owns edge e (vector load)
    f32x4 si = s[node];                       // wave-uniform
    f32x4 sj = s[jl];
    float xh = si.x + sj.y;                   // p_high[i] + q_high[j]
    float xl = si.z + sj.w;
    float lh = xh > 0.0f ? xh : 0.2f * xh;
    float ll = xl > 0.0f ? xl : 0.2f * xl;
    float wh = __expf(-lh);
    float wl = __expf(-ll);
    float rh = wh, rl = wl;                   // rowsum over RAW exp values
    #pragma unroll
    for (int o = 8; o > 0; o >>= 1) { rh += __shfl_xor(rh, o); rl += __shfl_xor(rl, o); }
    float eh = fminf(wh, 6.0f);               // relu6 on weights
    float el = fminf(wl, 6.0f);

    float acc_h = 0.0f, acc_l = 0.0f;
    #pragma unroll
    for (int half = 0; half < 2; half++) {
        unsigned int u[8];
        float weh[8], wel[8];
        #pragma unroll
        for (int t = 0; t < 8; t++) {
            int j = dp[half * 8 + t];                 // SGPR
            u[t] = HAGG[(size_t)j * 64 + lane];       // 8 independent loads in flight
        }
        #pragma unroll
        for (int t = 0; t < 8; t++) {
            weh[t] = __shfl(eh, half * 8 + t);        // batched broadcasts
            wel[t] = __shfl(el, half * 8 + t);
        }
        #pragma unroll
        for (int t = 0; t < 8; t++) {
            acc_h += weh[t] * lo_bf(u[t]);
            acc_l += wel[t] * hi_bf(u[t]);
        }
    }
    float r = 0.5f * (acc_h / rh + acc_l / rl);
    r = fminf(fmaxf(r, 0.0f), 6.0f);
    out[(size_t)node * 64 + lane] = r;
}

extern "C" void kernel_launch(void* const* d_in, const int* in_sizes, int n_in,
                              void* d_out, int out_size, void* d_ws, size_t ws_size,
                              hipStream_t stream) {
    const float* input = (const float*)d_in[0];
    const int*   edge  = (const int*)d_in[1];     // [2, E]: src then dst
    const float* Wh    = (const float*)d_in[2];
    const float* Wl    = (const float*)d_in[3];
    const float* ah    = (const float*)d_in[4];
    const float* al    = (const float*)d_in[5];
    float* out = (float*)d_out;

    unsigned int* H    = (unsigned int*)d_ws;                    // 25.6 MB
    unsigned int* HAGG = H + (size_t)N_NODES * 64;               // 25.6 MB
    f32x4* s = (f32x4*)(HAGG + (size_t)N_NODES * 64);            // 1.6 MB

    const int* dstp = edge + E_EDGES;

    k_gemm<<<1563, 256, 0, stream>>>(input, Wh, Wl, H);
    k_agg<<<N_NODES / 4, 256, 0, stream>>>(H, dstp, ah, al, HAGG, s);
    k_out<<<N_NODES / 4, 256, 0, stream>>>(HAGG, dstp, s, out);
}

// Round 5
// 228.797 us; speedup vs baseline: 1.1061x; 1.0167x over previous
//
#include <hip/hip_runtime.h>

#define N_NODES 100000
#define DEG 16
#define IN_F 128
#define OUT_F 64
#define E_EDGES (N_NODES * DEG)

typedef __bf16 bf16x8 __attribute__((ext_vector_type(8)));
typedef unsigned short u16x8 __attribute__((ext_vector_type(8)));
typedef float f32x4 __attribute__((ext_vector_type(4)));
typedef unsigned int u32x4 __attribute__((ext_vector_type(4)));

union BF8 { u16x8 u; bf16x8 b; };

__device__ inline float lo_bf(unsigned int u) {
    union { unsigned int i; float f; } v; v.i = u << 16; return v.f;
}
__device__ inline float hi_bf(unsigned int u) {
    union { unsigned int i; float f; } v; v.i = u & 0xFFFF0000u; return v.f;
}
__device__ inline unsigned short f2bf(float f) {
    union { float f; unsigned int i; } v; v.f = f;
    return (unsigned short)((v.i + 0x7FFFu + ((v.i >> 16) & 1u)) >> 16);
}
__device__ inline unsigned int packbf(float a, float b) {
    return (unsigned int)f2bf(a) | ((unsigned int)f2bf(b) << 16);
}

// ---------------- Kernel W: build pre-swizzled bf16 W image (LDS layout) ----
// Wimg: [2][64][136] u16; [m][n][k] = bf16(W_m[k*64 + n])   (W^T, stride 136)
__global__ __launch_bounds__(256) void k_wprep(
    const float* __restrict__ Wh, const float* __restrict__ Wl,
    unsigned short* __restrict__ Wimg)
{
    int idx = blockIdx.x * 256 + threadIdx.x;      // 64 blocks -> 16384 threads
    int m = idx >> 13;
    int rem = idx & 8191;
    int k = rem >> 6, n = rem & 63;
    float v = m ? Wl[rem] : Wh[rem];
    Wimg[m * 8704 + n * 136 + k] = f2bf(v);
}

// ---------------- Kernel A: H[row][n] = pack(bf16(in@Wh), bf16(in@Wl)) ----
// v2: W image copied dwordx4 from global; A-tile staged coalesced through LDS.
__global__ __launch_bounds__(256) void k_gemm(
    const float* __restrict__ in, const unsigned short* __restrict__ Wimg,
    unsigned int* __restrict__ H)
{
    __shared__ __align__(16) unsigned short ldsW[2][64][136];  // 34816 B
    __shared__ __align__(16) unsigned short ldsA[64][136];     // 17408 B

    // W image: 2176 x 16B chunks, straight copy
    {
        const u32x4* src = (const u32x4*)Wimg;
        u32x4* dst = (u32x4*)ldsW;
        for (int i = threadIdx.x; i < 2176; i += 256) dst[i] = src[i];
    }

    // A tile: 64 rows x 128 f32, fully coalesced f32x4 loads, packed b64 LDS writes
    int row0B = blockIdx.x * 64;
    {
        const f32x4* src = (const f32x4*)(in + (size_t)row0B * IN_F);
        #pragma unroll
        for (int i = 0; i < 8; i++) {
            int c = threadIdx.x + 256 * i;           // 2048 chunks of f32x4
            int row = c >> 5;                        // 32 chunks per row
            int kc = (c & 31) * 4;
            int grow = row0B + row;
            f32x4 v = (grow < N_NODES) ? src[c]
                      : *(const f32x4*)(in + (size_t)(N_NODES - 1) * IN_F + kc);
            unsigned int p0 = packbf(v[0], v[1]);
            unsigned int p1 = packbf(v[2], v[3]);
            *(unsigned int*)&ldsA[row][kc]     = p0;   // compiler merges to b64
            *(unsigned int*)&ldsA[row][kc + 2] = p1;
        }
    }
    __syncthreads();

    int wv = threadIdx.x >> 6;
    int lane = threadIdx.x & 63;
    int quad = lane >> 4, c = lane & 15;
    int row0 = row0B + wv * 16;

    // A fragment from LDS: lane holds A[m=c][k = quad*8 + j] per 32-wide k-block
    bf16x8 afrag[4];
    #pragma unroll
    for (int kb = 0; kb < 4; kb++) {
        BF8 a;
        a.u = *(const u16x8*)&ldsA[wv * 16 + c][kb * 32 + quad * 8];
        afrag[kb] = a.b;
    }

    f32x4 acc[2][4];
    #pragma unroll
    for (int m = 0; m < 2; m++)
        #pragma unroll
        for (int t = 0; t < 4; t++) acc[m][t] = (f32x4){0, 0, 0, 0};

    #pragma unroll
    for (int kb = 0; kb < 4; kb++) {
        #pragma unroll
        for (int t = 0; t < 4; t++) {
            int n = t * 16 + c;
            BF8 bh, bl;
            bh.u = *(const u16x8*)&ldsW[0][n][kb * 32 + quad * 8];
            bl.u = *(const u16x8*)&ldsW[1][n][kb * 32 + quad * 8];
            acc[0][t] = __builtin_amdgcn_mfma_f32_16x16x32_bf16(afrag[kb], bh.b, acc[0][t], 0, 0, 0);
            acc[1][t] = __builtin_amdgcn_mfma_f32_16x16x32_bf16(afrag[kb], bl.b, acc[1][t], 0, 0, 0);
        }
    }

    // C/D: col = t*16 + c, row = quad*4 + r  (proven mapping), packed u32 store
    #pragma unroll
    for (int r = 0; r < 4; r++) {
        int row = row0 + quad * 4 + r;
        if (row >= N_NODES) continue;
        size_t base = (size_t)row * OUT_F + c;
        #pragma unroll
        for (int t = 0; t < 4; t++)
            H[base + t * 16] = packbf(acc[0][t][r], acc[1][t][r]);
    }
}

// ---------------- Kernel B: HAGG + attention scalars s (R4-proven) ----
__global__ __launch_bounds__(256) void k_agg(
    const unsigned int* __restrict__ H, const int* __restrict__ dst,
    const float* __restrict__ ah, const float* __restrict__ al,
    unsigned int* __restrict__ HAGG, f32x4* __restrict__ s)
{
    int lane = threadIdx.x & 63;
    int node = __builtin_amdgcn_readfirstlane(blockIdx.x * 4 + (threadIdx.x >> 6));
    const int* dp = dst + node * DEG;   // 64-B aligned row, scalar loads

    unsigned int hu = H[(size_t)node * 64 + lane];
    float hh = lo_bf(hu);
    float hl = hi_bf(hu);
    float sh = 16.0f * hh;   // DEG * h[i] (self-loop among the 16 dst)
    float sl = 16.0f * hl;

    #pragma unroll
    for (int half = 0; half < 2; half++) {
        unsigned int u[8];
        #pragma unroll
        for (int t = 0; t < 8; t++) {
            int j = dp[half * 8 + t];                 // SGPR
            u[t] = H[(size_t)j * 64 + lane];          // 8 independent loads in flight
        }
        #pragma unroll
        for (int t = 0; t < 8; t++) { sh += lo_bf(u[t]); sl -= hi_bf(u[t]); }
    }
    HAGG[(size_t)node * 64 + lane] = packbf(sh, sl);

    float ph = hh * ah[lane];
    float qh = hh * ah[64 + lane];
    float pl = hl * al[lane];
    float ql = hl * al[64 + lane];
    #pragma unroll
    for (int o = 32; o > 0; o >>= 1) {
        ph += __shfl_xor(ph, o);
        qh += __shfl_xor(qh, o);
        pl += __shfl_xor(pl, o);
        ql += __shfl_xor(ql, o);
    }
    if (lane == 0) s[node] = (f32x4){ph, qh, pl, ql};
}

// ---------------- Kernel C: weighted aggregate + relu6 (R4-proven) ----
__global__ __launch_bounds__(256) void k_out(
    const unsigned int* __restrict__ HAGG, const int* __restrict__ dst,
    const f32x4* __restrict__ s, float* __restrict__ out)
{
    int lane = threadIdx.x & 63;
    int node = __builtin_amdgcn_readfirstlane(blockIdx.x * 4 + (threadIdx.x >> 6));
    const int* dp = dst + node * DEG;

    int jl = dp[lane & 15];                   // lane e<16 owns edge e
    f32x4 si = s[node];                       // wave-uniform
    f32x4 sj = s[jl];
    float xh = si.x + sj.y;                   // p_high[i] + q_high[j]
    float xl = si.z + sj.w;
    float lh = xh > 0.0f ? xh : 0.2f * xh;
    float ll = xl > 0.0f ? xl : 0.2f * xl;
    float wh = __expf(-lh);
    float wl = __expf(-ll);
    float rh = wh, rl = wl;                   // rowsum over RAW exp values
    #pragma unroll
    for (int o = 8; o > 0; o >>= 1) { rh += __shfl_xor(rh, o); rl += __shfl_xor(rl, o); }
    float eh = fminf(wh, 6.0f);               // relu6 on weights
    float el = fminf(wl, 6.0f);

    float acc_h = 0.0f, acc_l = 0.0f;
    #pragma unroll
    for (int half = 0; half < 2; half++) {
        unsigned int u[8];
        float weh[8], wel[8];
        #pragma unroll
        for (int t = 0; t < 8; t++) {
            int j = dp[half * 8 + t];                 // SGPR
            u[t] = HAGG[(size_t)j * 64 + lane];       // 8 independent loads in flight
        }
        #pragma unroll
        for (int t = 0; t < 8; t++) {
            weh[t] = __shfl(eh, half * 8 + t);
            wel[t] = __shfl(el, half * 8 + t);
        }
        #pragma unroll
        for (int t = 0; t < 8; t++) {
            acc_h += weh[t] * lo_bf(u[t]);
            acc_l += wel[t] * hi_bf(u[t]);
        }
    }
    float r = 0.5f * (acc_h / rh + acc_l / rl);
    r = fminf(fmaxf(r, 0.0f), 6.0f);
    out[(size_t)node * 64 + lane] = r;
}

extern "C" void kernel_launch(void* const* d_in, const int* in_sizes, int n_in,
                              void* d_out, int out_size, void* d_ws, size_t ws_size,
                              hipStream_t stream) {
    const float* input = (const float*)d_in[0];
    const int*   edge  = (const int*)d_in[1];     // [2, E]: src then dst
    const float* Wh    = (const float*)d_in[2];
    const float* Wl    = (const float*)d_in[3];
    const float* ah    = (const float*)d_in[4];
    const float* al    = (const float*)d_in[5];
    float* out = (float*)d_out;

    unsigned int* H    = (unsigned int*)d_ws;                    // 25.6 MB
    unsigned int* HAGG = H + (size_t)N_NODES * 64;               // 25.6 MB
    f32x4* s = (f32x4*)(HAGG + (size_t)N_NODES * 64);            // 1.6 MB
    unsigned short* Wimg = (unsigned short*)(s + N_NODES);       // 34816 B

    const int* dstp = edge + E_EDGES;

    k_wprep<<<64, 256, 0, stream>>>(Wh, Wl, Wimg);
    k_gemm<<<1563, 256, 0, stream>>>(input, Wimg, H);
    k_agg<<<N_NODES / 4, 256, 0, stream>>>(H, dstp, ah, al, HAGG, s);
    k_out<<<N_NODES / 4, 256, 0, stream>>>(HAGG, dstp, s, out);
}